// Round 15
// baseline (620.403 us; speedup 1.0000x reference)
//
#include <hip/hip_runtime.h>
#include <hip/hip_fp16.h>
#include <math.h>

#define NN   100000
#define HH   128
#define INF_ 35
#define GG   1000
#define GBM  128
#define NBINS 2048
#define DSCALE 128.0f      /* NBINS / 16.0 */
#define DINV   0.0078125f  /* 16.0 / NBINS */
#define DCLAMP 15.992f     /* ensures bin <= 2046 */

typedef __attribute__((ext_vector_type(8))) short short8;
typedef __attribute__((ext_vector_type(4))) float f32x4;

static __device__ __forceinline__ float silu_f(float x){ return x / (1.f + __expf(-x)); }
static __device__ __forceinline__ unsigned bf16rne(float x){
    unsigned u = __float_as_uint(x);
    return (u + 0x7FFFu + ((u>>16)&1u)) >> 16;
}
#define BN_INV 0.9999950000374997f  /* 1/sqrt(1+1e-5) */

// ---------------- stacked CSR: count ----------------
__global__ void k_count(const int* __restrict__ ei1, const int* __restrict__ ei2,
                        int E1, int E2, int n, int* __restrict__ deg){
    int e = blockIdx.x*256 + threadIdx.x;
    int ET = E1 + E2;
    if (e >= ET) return;
    int c;
    if (e < E1) c = ei1[E1 + e];
    else        c = n + ei2[E2 + (e - E1)];
    atomicAdd(&deg[c], 1);
}

// ---------------- single-kernel decoupled-lookback exclusive scan ----------------
__global__ void k_scan_lb(const int* __restrict__ deg, int n2, int* __restrict__ off,
                          int* __restrict__ agg, int* __restrict__ incl,
                          unsigned* __restrict__ flags, int ET){
    __shared__ int s[256];
    __shared__ int exc_sh;
    int blk = blockIdx.x, tid = threadIdx.x;
    int i = blk*256 + tid;
    int v = (i<n2)? deg[i] : 0;
    s[tid] = v; __syncthreads();
    for (int ofs=1; ofs<256; ofs<<=1){
        int t = (tid>=ofs)? s[tid-ofs] : 0;
        __syncthreads(); s[tid] += t; __syncthreads();
    }
    if (tid == 0){
        int total = s[255];
        atomicExch(&agg[blk], total);
        __threadfence();
        atomicExch(&flags[blk], 1u);
        int exc = 0;
        int pb = blk - 1;
        while (pb >= 0){
            unsigned f;
            do { f = atomicAdd(&flags[pb], 0u); } while (f == 0u);
            if (f == 2u){ exc += atomicAdd(&incl[pb], 0); break; }
            exc += atomicAdd(&agg[pb], 0);
            pb--;
        }
        atomicExch(&incl[blk], exc + total);
        __threadfence();
        atomicExch(&flags[blk], 2u);
        exc_sh = exc;
    }
    __syncthreads();
    if (i < n2) off[i] = exc_sh + s[tid] - v;
    if (i == 0) off[n2] = ET;
}

// ---------------- fused build: nodeW pack + Wtg + fp16 (v,slope) tables + CSR fill ----------------
// blocks [0,48): pack ; [48,66): Wtg ; [66,6210): table ; [6210,..): fill
__global__ void k_build(const float* __restrict__ nodeW,
                        const float* __restrict__ coordW, const float* __restrict__ coordB,
                        const float* __restrict__ W_in,
                        const int* __restrict__ ei1, const int* __restrict__ ei2,
                        int E1, int E2, int n, const float* __restrict__ pos,
                        const int* __restrict__ off, int* __restrict__ cur,
                        unsigned short* __restrict__ Bpk, unsigned short* __restrict__ tabs,
                        float* __restrict__ Wtg, float2* __restrict__ rec){
    int blk = blockIdx.x, tx = threadIdx.x;
    if (blk < 48){
        int idx = blk*256 + tx;
        if (idx >= 6*2048) return;
        int li = idx >> 11;
        int r  = idx & 2047;
        int s  = r >> 9;
        int r2 = r & 511;
        int ct = r2 >> 6;
        int l  = r2 & 63;
        const float* src = nodeW + (size_t)li*16384 + (size_t)(s*32 + (l>>4)*8)*HH + ct*16 + (l&15);
        unsigned short o[8];
        #pragma unroll
        for (int j=0;j<8;j++) o[j] = (unsigned short)bf16rne(src[(size_t)j*HH]);
        uint4 v;
        v.x = o[0] | ((unsigned)o[1]<<16);
        v.y = o[2] | ((unsigned)o[3]<<16);
        v.z = o[4] | ((unsigned)o[5]<<16);
        v.w = o[6] | ((unsigned)o[7]<<16);
        *(uint4*)(Bpk + (size_t)idx*8) = v;
    } else if (blk < 66){
        int i = (blk-48)*256 + tx;
        if (i >= 128*36) return;
        int c = i/36, k = i - c*36;
        Wtg[i] = (k < INF_) ? W_in[k*HH + c] : 0.f;
    } else if (blk < 66+6144){
        int idx = (blk-66)*256 + tx;
        if (idx >= 6*NBINS*HH) return;
        int li  = idx / (NBINS*HH);
        int rem = idx - li*(NBINS*HH);
        int bin = rem >> 7;
        int col = rem & 127;
        float d0 = (float)bin * DINV;
        float d1 = d0 + DINV;
        const float* cW = coordW + (size_t)li*9*HH;
        float cb = coordB[li*HH + col];
        float q0 = cb, q1 = cb;
        #pragma unroll
        for (int k=0;k<9;k++){
            float wk = cW[k*HH + col];
            float t0 = 1.5f*d0 - 1.125f*(float)k;
            float t1 = 1.5f*d1 - 1.125f*(float)k;
            q0 += __expf(-t0*t0) * wk;
            q1 += __expf(-t1*t1) * wk;
        }
        float v = silu_f(q0);
        float s = silu_f(q1) - v;
        tabs[(size_t)idx*2+0] = __half_as_ushort(__float2half_rn(v));
        tabs[(size_t)idx*2+1] = __half_as_ushort(__float2half_rn(s));
    } else {
        int e = (blk - (66+6144))*256 + tx;
        int ET = E1 + E2;
        if (e >= ET) return;
        int r, creal, cslot;
        if (e < E1){ r = ei1[e];        creal = ei1[E1 + e];        cslot = creal; }
        else       { int ee = e - E1; r = ei2[ee]; creal = ei2[E2 + ee]; cslot = n + creal; }
        int slot = atomicAdd(&cur[cslot], 1);
        int p = off[cslot] + slot;
        float dx = pos[r*3+0]-pos[creal*3+0];
        float dy = pos[r*3+1]-pos[creal*3+1];
        float dz = pos[r*3+2]-pos[creal*3+2];
        float d  = sqrtf(dx*dx + dy*dy + dz*dz);
        rec[p] = make_float2(__int_as_float(r), d);
    }
}

// ---------------- input: hb = bf16(silu(x @ W_in + b)); W streamed from L2 ----------------
#define NT_IN (NN/16)
__global__ __launch_bounds__(256) void k_input(const float* __restrict__ x,
        const float* __restrict__ Wtg, const float* __restrict__ b,
        unsigned short* __restrict__ hb){
    __shared__ __align__(16) float xs[16][36];
    int tx = threadIdx.x;
    int c = tx & 127, g = tx >> 7;
    float bc = b[c];
    const float4* wp = (const float4*)(Wtg + c*36);
    for (int tile = blockIdx.x; tile < NT_IN; tile += gridDim.x){
        int r0 = tile*16;
        for (int i = tx; i < 16*INF_; i += 256){
            int rr = i/INF_, kk = i - rr*INF_;
            xs[rr][kk] = x[(size_t)(r0+rr)*INF_ + kk];
        }
        if (tx < 16) xs[tx][35] = 0.f;
        __syncthreads();
        float acc[8];
        #pragma unroll
        for (int j=0;j<8;j++) acc[j] = bc;
        #pragma unroll
        for (int kk=0;kk<9;kk++){
            float4 w4 = wp[kk];
            #pragma unroll
            for (int j=0;j<8;j++){
                float4 xv = *(const float4*)(&xs[g*8+j][kk*4]);
                acc[j] += xv.x*w4.x + xv.y*w4.y + xv.z*w4.z + xv.w*w4.w;
            }
        }
        #pragma unroll
        for (int j=0;j<8;j++){
            int gr = r0 + g*8 + j;
            hb[(size_t)gr*HH + c] = (unsigned short)bf16rne(silu_f(acc[j]));
        }
        __syncthreads();
    }
}

// ---------------- merged dual-branch gather: fp16 (v,slope) table, bf16 h, 4-edge unroll ----------------
#define GEDGE(RP, S_, B_, F_)                                        \
    int S_ = __float_as_int((RP).x);                                 \
    float db_##S_ = fminf((RP).y, DCLAMP)*DSCALE;                    \
    int B_ = (int)db_##S_; float F_ = db_##S_ - (float)B_;

#define GACC(U_, T_, F_)                                             \
    {                                                                \
        float2 p0 = __half22float2(*(const __half2*)&(T_).x);        \
        float2 p1 = __half22float2(*(const __half2*)&(T_).y);        \
        acc.x += __uint_as_float((U_)<<16)           * (p0.x + p0.y*(F_)); \
        acc.y += __uint_as_float((U_) & 0xFFFF0000u) * (p1.x + p1.y*(F_)); \
    }

__global__ __launch_bounds__(256) void k_gather(
        const unsigned short* __restrict__ hb,
        const int* __restrict__ off, const float2* __restrict__ rec,
        const unsigned short* __restrict__ tab0, const unsigned short* __restrict__ tab1,
        unsigned short* __restrict__ aggb1, unsigned short* __restrict__ aggb2,
        int n, int nblk1){
    int b = blockIdx.x;
    int br = (b >= nblk1) ? 1 : 0;
    int node = (br ? b - nblk1 : b)*4 + (threadIdx.x>>6);
    if (node >= n) return;
    int c = (threadIdx.x & 63)*2;
    const unsigned short* tab = br ? tab1 : tab0;
    unsigned short* aggp = br ? aggb2 : aggb1;

    float2 acc;
    {
        unsigned u = *(const unsigned*)(hb + (size_t)node*HH + c);
        acc.x = __uint_as_float(u<<16); acc.y = __uint_as_float(u & 0xFFFF0000u);
    }

    int slot = node + br*n;
    int lo = off[slot], hi = off[slot+1];
    lo = __builtin_amdgcn_readfirstlane(lo);
    hi = __builtin_amdgcn_readfirstlane(hi);

    int p = lo;
    for (; p+4<=hi; p+=4){
        float2 r0 = rec[p], r1 = rec[p+1], r2 = rec[p+2], r3 = rec[p+3];
        GEDGE(r0, s0, b0, f0)
        GEDGE(r1, s1, b1, f1)
        GEDGE(r2, s2, b2, f2)
        GEDGE(r3, s3, b3, f3)
        unsigned u0 = *(const unsigned*)(hb + (size_t)s0*HH + c);
        unsigned u1 = *(const unsigned*)(hb + (size_t)s1*HH + c);
        unsigned u2 = *(const unsigned*)(hb + (size_t)s2*HH + c);
        unsigned u3 = *(const unsigned*)(hb + (size_t)s3*HH + c);
        uint2 t0 = *(const uint2*)(tab + ((size_t)b0*HH + c)*2);
        uint2 t1 = *(const uint2*)(tab + ((size_t)b1*HH + c)*2);
        uint2 t2 = *(const uint2*)(tab + ((size_t)b2*HH + c)*2);
        uint2 t3 = *(const uint2*)(tab + ((size_t)b3*HH + c)*2);
        GACC(u0, t0, f0)
        GACC(u1, t1, f1)
        GACC(u2, t2, f2)
        GACC(u3, t3, f3)
    }
    for (; p+2<=hi; p+=2){
        float2 r0 = rec[p], r1 = rec[p+1];
        GEDGE(r0, s0, b0, f0)
        GEDGE(r1, s1, b1, f1)
        unsigned u0 = *(const unsigned*)(hb + (size_t)s0*HH + c);
        unsigned u1 = *(const unsigned*)(hb + (size_t)s1*HH + c);
        uint2 t0 = *(const uint2*)(tab + ((size_t)b0*HH + c)*2);
        uint2 t1 = *(const uint2*)(tab + ((size_t)b1*HH + c)*2);
        GACC(u0, t0, f0)
        GACC(u1, t1, f1)
    }
    if (p < hi){
        float2 r0 = rec[p];
        GEDGE(r0, s0, b0, f0)
        unsigned u0 = *(const unsigned*)(hb + (size_t)s0*HH + c);
        uint2 t0 = *(const uint2*)(tab + ((size_t)b0*HH + c)*2);
        GACC(u0, t0, f0)
    }
    unsigned pk = bf16rne(acc.x) | (bf16rne(acc.y)<<16);
    *(unsigned*)(aggp + (size_t)node*HH + c) = pk;
}

// ---------------- dual-branch node GEMM via MFMA bf16: 32 rows/wave (B frags amortized 2x) ----------------
__global__ __launch_bounds__(256) void k_gemm2m(
        const unsigned short* __restrict__ A1, const unsigned short* __restrict__ A2,
        const unsigned short* __restrict__ Bp0, const unsigned short* __restrict__ Bp1,
        const float* __restrict__ b1, const float* __restrict__ b2,
        const float* __restrict__ g1, const float* __restrict__ g2,
        const float* __restrict__ e1, const float* __restrict__ e2,
        float* __restrict__ C, unsigned short* __restrict__ Cb, int n){
    int tx = threadIdx.x;
    int l = tx & 63, wv = tx >> 6;
    int rb = blockIdx.x*GBM + wv*32;
    int mlo = l & 15, khi = l >> 4;
    int ar0 = rb + mlo, ar1 = rb + 16 + mlo;
    bool ok0 = ar0 < n, ok1 = ar1 < n;

    f32x4 accA[2][8], accB[2][8];
    #pragma unroll
    for (int rh=0;rh<2;rh++)
        #pragma unroll
        for (int ct=0;ct<8;ct++){ accA[rh][ct] = (f32x4)0.f; accB[rh][ct] = (f32x4)0.f; }

    {   // branch 0
        short8 af0[4], af1[4];
        const short8* ap0 = (const short8*)(A1 + (size_t)ar0*HH);
        const short8* ap1 = (const short8*)(A1 + (size_t)ar1*HH);
        #pragma unroll
        for (int s=0;s<4;s++){
            af0[s] = ok0 ? ap0[s*4 + khi] : (short8)0;
            af1[s] = ok1 ? ap1[s*4 + khi] : (short8)0;
        }
        const short8* bp = (const short8*)Bp0;
        #pragma unroll
        for (int s=0;s<4;s++){
            #pragma unroll
            for (int ct=0;ct<8;ct++){
                short8 bf = bp[s*512 + ct*64 + l];
                accA[0][ct] = __builtin_amdgcn_mfma_f32_16x16x32_bf16(af0[s], bf, accA[0][ct], 0, 0, 0);
                accA[1][ct] = __builtin_amdgcn_mfma_f32_16x16x32_bf16(af1[s], bf, accA[1][ct], 0, 0, 0);
            }
        }
    }
    {   // branch 1
        short8 af0[4], af1[4];
        const short8* ap0 = (const short8*)(A2 + (size_t)ar0*HH);
        const short8* ap1 = (const short8*)(A2 + (size_t)ar1*HH);
        #pragma unroll
        for (int s=0;s<4;s++){
            af0[s] = ok0 ? ap0[s*4 + khi] : (short8)0;
            af1[s] = ok1 ? ap1[s*4 + khi] : (short8)0;
        }
        const short8* bp = (const short8*)Bp1;
        #pragma unroll
        for (int s=0;s<4;s++){
            #pragma unroll
            for (int ct=0;ct<8;ct++){
                short8 bf = bp[s*512 + ct*64 + l];
                accB[0][ct] = __builtin_amdgcn_mfma_f32_16x16x32_bf16(af0[s], bf, accB[0][ct], 0, 0, 0);
                accB[1][ct] = __builtin_amdgcn_mfma_f32_16x16x32_bf16(af1[s], bf, accB[1][ct], 0, 0, 0);
            }
        }
    }

    #pragma unroll
    for (int ct=0;ct<8;ct++){
        int ncol = ct*16 + mlo;
        float bi1 = b1[ncol], ga1 = g1[ncol], bt1 = e1[ncol];
        float bi2 = b2[ncol], ga2 = g2[ncol], bt2 = e2[ncol];
        #pragma unroll
        for (int rh=0;rh<2;rh++){
            #pragma unroll
            for (int r=0;r<4;r++){
                int grow = rb + rh*16 + khi*4 + r;
                if (grow < n){
                    float xv = accA[rh][ct][r] + bi1;
                    xv = (xv>=0.f)? xv : 0.01f*xv;
                    float yv = accB[rh][ct][r] + bi2;
                    yv = (yv>=0.f)? yv : 0.01f*yv;
                    float o = (ga1*xv + ga2*yv)*BN_INV + bt1 + bt2;
                    if (C) C[(size_t)grow*HH + ncol] = o;
                    Cb[(size_t)grow*HH + ncol] = (unsigned short)bf16rne(o);
                }
            }
        }
    }
}

// ---------------- fused pool + FC x3 + head ----------------
static __device__ __forceinline__ int lower_bound_i(const int* __restrict__ a, int n, int key){
    int lo=0, hi=n;
    while (lo<hi){ int m=(lo+hi)>>1; if (a[m]<key) lo=m+1; else hi=m; }
    return lo;
}
__global__ void k_poolfc(const float* __restrict__ h,
                     const int* __restrict__ batch,
                     const float* __restrict__ fcW, const float* __restrict__ fcB,
                     const float* __restrict__ fbg, const float* __restrict__ fbb,
                     const float* __restrict__ outW, const float* __restrict__ outB,
                     float* __restrict__ out, int n){
    __shared__ float row[HH];
    __shared__ float red[2];
    int g = blockIdx.x, c = threadIdx.x;
    int lo = lower_bound_i(batch, n, g);
    int hi = lower_bound_i(batch, n, g+1);
    float v = 0.f;
    for (int r=lo; r<hi; r++) v += h[(size_t)r*HH + c];
    for (int l=0;l<3;l++){
        row[c] = v; __syncthreads();
        float acc = fcB[l*HH + c];
        const float* W = fcW + (size_t)l*HH*HH;
        #pragma unroll 8
        for (int k=0;k<HH;k++) acc += row[k]*W[k*HH + c];
        acc = (acc>=0.f)? acc : 0.01f*acc;
        v = fbg[l*HH+c]*acc*BN_INV + fbb[l*HH+c];
        __syncthreads();
    }
    float t = v * outW[c];
    #pragma unroll
    for (int o=32;o>0;o>>=1) t += __shfl_down(t, o, 64);
    if ((c&63)==0) red[c>>6] = t;
    __syncthreads();
    if (c==0) out[g] = red[0] + red[1] + outB[0];
}

extern "C" void kernel_launch(void* const* d_in, const int* in_sizes, int n_in,
                              void* d_out, int out_size, void* d_ws, size_t ws_size,
                              hipStream_t stream){
    const float* x      = (const float*)d_in[0];
    const float* pos    = (const float*)d_in[1];
    const float* W_in   = (const float*)d_in[2];
    const float* b_in   = (const float*)d_in[3];
    const float* coordW = (const float*)d_in[4];
    const float* coordB = (const float*)d_in[5];
    const float* nodeW  = (const float*)d_in[6];
    const float* nodeB  = (const float*)d_in[7];
    const float* bnG    = (const float*)d_in[8];
    const float* bnB    = (const float*)d_in[9];
    const float* fcW    = (const float*)d_in[10];
    const float* fcB    = (const float*)d_in[11];
    const float* fcBnG  = (const float*)d_in[12];
    const float* fcBnB  = (const float*)d_in[13];
    const float* outW   = (const float*)d_in[14];
    const float* outB   = (const float*)d_in[15];
    const int* ei1      = (const int*)d_in[16];
    const int* ei2      = (const int*)d_in[17];
    const int* batch    = (const int*)d_in[18];
    const int E1 = in_sizes[16]/2, E2 = in_sizes[17]/2;
    const int n = NN;
    const int n2 = 2*n;
    const int ET = E1 + E2;

    char* w = (char*)d_ws;
    size_t o = 0;
    auto alloc = [&](size_t bytes)->void*{
        void* r = w + o;
        o += (bytes + 255) & ~(size_t)255;
        return r;
    };
    unsigned short* hb    = (unsigned short*)alloc((size_t)n*HH*2);
    unsigned short* hb2   = (unsigned short*)alloc((size_t)n*HH*2);
    unsigned short* aggb1 = (unsigned short*)alloc((size_t)n*HH*2);
    unsigned short* aggb2 = (unsigned short*)alloc((size_t)n*HH*2);
    unsigned short* Bpk   = (unsigned short*)alloc((size_t)6*16384*2);
    unsigned short* tabs  = (unsigned short*)alloc((size_t)6*NBINS*HH*4);  // fp16 (v,slope)
    float*  Wtg  = (float*)alloc((size_t)128*36*4);
    int*    off  = (int*)alloc((size_t)(n2+1)*4);
    int*    cnt  = (int*)alloc((size_t)n2*4);     // cnt, cur, flags contiguous -> one memset
    int*    cur  = (int*)alloc((size_t)n2*4);
    unsigned* flags = (unsigned*)alloc(1024*4);
    int*    aggl = (int*)alloc(1024*4);
    int*    incl = (int*)alloc(1024*4);
    float2* rec  = (float2*)alloc((size_t)ET*8);
    float*  hfin = (float*)alloc((size_t)n*HH*4);
    (void)n_in; (void)out_size; (void)ws_size;

    int nb2 = (n2+255)/256;   // 782 scan blocks

    hipMemsetAsync(cnt, 0, (size_t)(2*n2 + 1024)*4, stream);
    k_count<<<(ET+255)/256,256,0,stream>>>(ei1, ei2, E1, E2, n, cnt);
    k_scan_lb<<<nb2,256,0,stream>>>(cnt, n2, off, aggl, incl, flags, ET);
    k_build<<<66+6144+(ET+255)/256,256,0,stream>>>(nodeW, coordW, coordB, W_in,
        ei1, ei2, E1, E2, n, pos, off, cur, Bpk, tabs, Wtg, rec);

    k_input<<<2048,256,0,stream>>>(x, Wtg, b_in, hb);

    int nb4 = (n+3)/4;
    unsigned short* hbcur = hb;
    unsigned short* hboth = hb2;
    for (int l=0; l<3; l++){
        int li0 = l*2, li1 = l*2+1;
        float* Cout = (l==2) ? hfin : nullptr;       // fp32 out only on final layer (poolfc)
        k_gather<<<2*nb4,256,0,stream>>>(hbcur, off, rec,
            tabs + (size_t)li0*NBINS*HH*2, tabs + (size_t)li1*NBINS*HH*2,
            aggb1, aggb2, n, nb4);
        k_gemm2m<<<(n+GBM-1)/GBM,256,0,stream>>>(aggb1, aggb2,
            Bpk + (size_t)li0*16384, Bpk + (size_t)li1*16384,
            nodeB + (size_t)li0*HH,  nodeB + (size_t)li1*HH,
            bnG   + (size_t)li0*HH,  bnG   + (size_t)li1*HH,
            bnB   + (size_t)li0*HH,  bnB   + (size_t)li1*HH,
            Cout, hboth, n);
        unsigned short* tb = hbcur; hbcur = hboth; hboth = tb;
    }

    k_poolfc<<<GG,128,0,stream>>>(hfin, batch, fcW, fcB, fcBnG, fcBnB, outW, outB, (float*)d_out, n);
}

// Round 16
// 506.332 us; speedup vs baseline: 1.2253x; 1.2253x over previous
//
#include <hip/hip_runtime.h>
#include <hip/hip_fp16.h>
#include <math.h>

#define NN   100000
#define HH   128
#define INF_ 35
#define GG   1000
#define LBM  64
#define NBINS 2048
#define DSCALE 128.0f      /* NBINS / 16.0 */
#define DINV   0.0078125f  /* 16.0 / NBINS */
#define DCLAMP 15.992f     /* ensures bin <= 2046 */

typedef __attribute__((ext_vector_type(8))) short short8;
typedef __attribute__((ext_vector_type(4))) float f32x4;

static __device__ __forceinline__ float silu_f(float x){ return x / (1.f + __expf(-x)); }
static __device__ __forceinline__ unsigned bf16rne(float x){
    unsigned u = __float_as_uint(x);
    return (u + 0x7FFFu + ((u>>16)&1u)) >> 16;
}
#define BN_INV 0.9999950000374997f  /* 1/sqrt(1+1e-5) */

// ---------------- stacked CSR: count ----------------
__global__ void k_count(const int* __restrict__ ei1, const int* __restrict__ ei2,
                        int E1, int E2, int n, int* __restrict__ deg){
    int e = blockIdx.x*256 + threadIdx.x;
    int ET = E1 + E2;
    if (e >= ET) return;
    int c;
    if (e < E1) c = ei1[E1 + e];
    else        c = n + ei2[E2 + (e - E1)];
    atomicAdd(&deg[c], 1);
}

// ---------------- single-kernel decoupled-lookback exclusive scan ----------------
__global__ void k_scan_lb(const int* __restrict__ deg, int n2, int* __restrict__ off,
                          int* __restrict__ agg, int* __restrict__ incl,
                          unsigned* __restrict__ flags, int ET){
    __shared__ int s[256];
    __shared__ int exc_sh;
    int blk = blockIdx.x, tid = threadIdx.x;
    int i = blk*256 + tid;
    int v = (i<n2)? deg[i] : 0;
    s[tid] = v; __syncthreads();
    for (int ofs=1; ofs<256; ofs<<=1){
        int t = (tid>=ofs)? s[tid-ofs] : 0;
        __syncthreads(); s[tid] += t; __syncthreads();
    }
    if (tid == 0){
        int total = s[255];
        atomicExch(&agg[blk], total);
        __threadfence();
        atomicExch(&flags[blk], 1u);
        int exc = 0;
        int pb = blk - 1;
        while (pb >= 0){
            unsigned f;
            do { f = atomicAdd(&flags[pb], 0u); } while (f == 0u);
            if (f == 2u){ exc += atomicAdd(&incl[pb], 0); break; }
            exc += atomicAdd(&agg[pb], 0);
            pb--;
        }
        atomicExch(&incl[blk], exc + total);
        __threadfence();
        atomicExch(&flags[blk], 2u);
        exc_sh = exc;
    }
    __syncthreads();
    if (i < n2) off[i] = exc_sh + s[tid] - v;
    if (i == 0) off[n2] = ET;
}

// ---------------- fused build: nodeW pack + Wtg + fp16 (v,slope) tables + CSR fill ----------------
// blocks [0,48): pack ; [48,66): Wtg ; [66,6210): table ; [6210,..): fill
__global__ void k_build(const float* __restrict__ nodeW,
                        const float* __restrict__ coordW, const float* __restrict__ coordB,
                        const float* __restrict__ W_in,
                        const int* __restrict__ ei1, const int* __restrict__ ei2,
                        int E1, int E2, int n, const float* __restrict__ pos,
                        const int* __restrict__ off, int* __restrict__ cur,
                        unsigned short* __restrict__ Bpk, unsigned short* __restrict__ tabs,
                        float* __restrict__ Wtg, float2* __restrict__ rec){
    int blk = blockIdx.x, tx = threadIdx.x;
    if (blk < 48){
        int idx = blk*256 + tx;
        if (idx >= 6*2048) return;
        int li = idx >> 11;
        int r  = idx & 2047;
        int s  = r >> 9;
        int r2 = r & 511;
        int ct = r2 >> 6;
        int l  = r2 & 63;
        const float* src = nodeW + (size_t)li*16384 + (size_t)(s*32 + (l>>4)*8)*HH + ct*16 + (l&15);
        unsigned short o[8];
        #pragma unroll
        for (int j=0;j<8;j++) o[j] = (unsigned short)bf16rne(src[(size_t)j*HH]);
        uint4 v;
        v.x = o[0] | ((unsigned)o[1]<<16);
        v.y = o[2] | ((unsigned)o[3]<<16);
        v.z = o[4] | ((unsigned)o[5]<<16);
        v.w = o[6] | ((unsigned)o[7]<<16);
        *(uint4*)(Bpk + (size_t)idx*8) = v;
    } else if (blk < 66){
        int i = (blk-48)*256 + tx;
        if (i >= 128*36) return;
        int c = i/36, k = i - c*36;
        Wtg[i] = (k < INF_) ? W_in[k*HH + c] : 0.f;
    } else if (blk < 66+6144){
        int idx = (blk-66)*256 + tx;
        if (idx >= 6*NBINS*HH) return;
        int li  = idx / (NBINS*HH);
        int rem = idx - li*(NBINS*HH);
        int bin = rem >> 7;
        int col = rem & 127;
        float d0 = (float)bin * DINV;
        float d1 = d0 + DINV;
        const float* cW = coordW + (size_t)li*9*HH;
        float cb = coordB[li*HH + col];
        float q0 = cb, q1 = cb;
        #pragma unroll
        for (int k=0;k<9;k++){
            float wk = cW[k*HH + col];
            float t0 = 1.5f*d0 - 1.125f*(float)k;
            float t1 = 1.5f*d1 - 1.125f*(float)k;
            q0 += __expf(-t0*t0) * wk;
            q1 += __expf(-t1*t1) * wk;
        }
        float v = silu_f(q0);
        float s = silu_f(q1) - v;
        tabs[(size_t)idx*2+0] = __half_as_ushort(__float2half_rn(v));
        tabs[(size_t)idx*2+1] = __half_as_ushort(__float2half_rn(s));
    } else {
        int e = (blk - (66+6144))*256 + tx;
        int ET = E1 + E2;
        if (e >= ET) return;
        int r, creal, cslot;
        if (e < E1){ r = ei1[e];        creal = ei1[E1 + e];        cslot = creal; }
        else       { int ee = e - E1; r = ei2[ee]; creal = ei2[E2 + ee]; cslot = n + creal; }
        int slot = atomicAdd(&cur[cslot], 1);
        int p = off[cslot] + slot;
        float dx = pos[r*3+0]-pos[creal*3+0];
        float dy = pos[r*3+1]-pos[creal*3+1];
        float dz = pos[r*3+2]-pos[creal*3+2];
        float d  = sqrtf(dx*dx + dy*dy + dz*dz);
        rec[p] = make_float2(__int_as_float(r), d);
    }
}

// ---------------- input: hb = bf16(silu(x @ W_in + b)); W streamed from L2 ----------------
#define NT_IN (NN/16)
__global__ __launch_bounds__(256) void k_input(const float* __restrict__ x,
        const float* __restrict__ Wtg, const float* __restrict__ b,
        unsigned short* __restrict__ hb){
    __shared__ __align__(16) float xs[16][36];
    int tx = threadIdx.x;
    int c = tx & 127, g = tx >> 7;
    float bc = b[c];
    const float4* wp = (const float4*)(Wtg + c*36);
    for (int tile = blockIdx.x; tile < NT_IN; tile += gridDim.x){
        int r0 = tile*16;
        for (int i = tx; i < 16*INF_; i += 256){
            int rr = i/INF_, kk = i - rr*INF_;
            xs[rr][kk] = x[(size_t)(r0+rr)*INF_ + kk];
        }
        if (tx < 16) xs[tx][35] = 0.f;
        __syncthreads();
        float acc[8];
        #pragma unroll
        for (int j=0;j<8;j++) acc[j] = bc;
        #pragma unroll
        for (int kk=0;kk<9;kk++){
            float4 w4 = wp[kk];
            #pragma unroll
            for (int j=0;j<8;j++){
                float4 xv = *(const float4*)(&xs[g*8+j][kk*4]);
                acc[j] += xv.x*w4.x + xv.y*w4.y + xv.z*w4.z + xv.w*w4.w;
            }
        }
        #pragma unroll
        for (int j=0;j<8;j++){
            int gr = r0 + g*8 + j;
            hb[(size_t)gr*HH + c] = (unsigned short)bf16rne(silu_f(acc[j]));
        }
        __syncthreads();
    }
}

// ---------------- merged dual-branch gather: fp16 (v,slope) table, bf16 h, 4-edge unroll ----------------
#define GEDGE(RP, S_, B_, F_)                                        \
    int S_ = __float_as_int((RP).x);                                 \
    float db_##S_ = fminf((RP).y, DCLAMP)*DSCALE;                    \
    int B_ = (int)db_##S_; float F_ = db_##S_ - (float)B_;

#define GACC(U_, T_, F_)                                             \
    {                                                                \
        float2 p0 = __half22float2(*(const __half2*)&(T_).x);        \
        float2 p1 = __half22float2(*(const __half2*)&(T_).y);        \
        acc.x += __uint_as_float((U_)<<16)           * (p0.x + p0.y*(F_)); \
        acc.y += __uint_as_float((U_) & 0xFFFF0000u) * (p1.x + p1.y*(F_)); \
    }

__global__ __launch_bounds__(256) void k_gather(
        const unsigned short* __restrict__ hb,
        const int* __restrict__ off, const float2* __restrict__ rec,
        const unsigned short* __restrict__ tab0, const unsigned short* __restrict__ tab1,
        unsigned short* __restrict__ aggb1, unsigned short* __restrict__ aggb2,
        int n, int nblk1){
    int b = blockIdx.x;
    int br = (b >= nblk1) ? 1 : 0;
    int node = (br ? b - nblk1 : b)*4 + (threadIdx.x>>6);
    if (node >= n) return;
    int c = (threadIdx.x & 63)*2;
    const unsigned short* tab = br ? tab1 : tab0;
    unsigned short* aggp = br ? aggb2 : aggb1;

    float2 acc;
    {
        unsigned u = *(const unsigned*)(hb + (size_t)node*HH + c);
        acc.x = __uint_as_float(u<<16); acc.y = __uint_as_float(u & 0xFFFF0000u);
    }

    int slot = node + br*n;
    int lo = off[slot], hi = off[slot+1];
    lo = __builtin_amdgcn_readfirstlane(lo);
    hi = __builtin_amdgcn_readfirstlane(hi);

    int p = lo;
    for (; p+4<=hi; p+=4){
        float2 r0 = rec[p], r1 = rec[p+1], r2 = rec[p+2], r3 = rec[p+3];
        GEDGE(r0, s0, b0, f0)
        GEDGE(r1, s1, b1, f1)
        GEDGE(r2, s2, b2, f2)
        GEDGE(r3, s3, b3, f3)
        unsigned u0 = *(const unsigned*)(hb + (size_t)s0*HH + c);
        unsigned u1 = *(const unsigned*)(hb + (size_t)s1*HH + c);
        unsigned u2 = *(const unsigned*)(hb + (size_t)s2*HH + c);
        unsigned u3 = *(const unsigned*)(hb + (size_t)s3*HH + c);
        uint2 t0 = *(const uint2*)(tab + ((size_t)b0*HH + c)*2);
        uint2 t1 = *(const uint2*)(tab + ((size_t)b1*HH + c)*2);
        uint2 t2 = *(const uint2*)(tab + ((size_t)b2*HH + c)*2);
        uint2 t3 = *(const uint2*)(tab + ((size_t)b3*HH + c)*2);
        GACC(u0, t0, f0)
        GACC(u1, t1, f1)
        GACC(u2, t2, f2)
        GACC(u3, t3, f3)
    }
    for (; p+2<=hi; p+=2){
        float2 r0 = rec[p], r1 = rec[p+1];
        GEDGE(r0, s0, b0, f0)
        GEDGE(r1, s1, b1, f1)
        unsigned u0 = *(const unsigned*)(hb + (size_t)s0*HH + c);
        unsigned u1 = *(const unsigned*)(hb + (size_t)s1*HH + c);
        uint2 t0 = *(const uint2*)(tab + ((size_t)b0*HH + c)*2);
        uint2 t1 = *(const uint2*)(tab + ((size_t)b1*HH + c)*2);
        GACC(u0, t0, f0)
        GACC(u1, t1, f1)
    }
    if (p < hi){
        float2 r0 = rec[p];
        GEDGE(r0, s0, b0, f0)
        unsigned u0 = *(const unsigned*)(hb + (size_t)s0*HH + c);
        uint2 t0 = *(const uint2*)(tab + ((size_t)b0*HH + c)*2);
        GACC(u0, t0, f0)
    }
    unsigned pk = bf16rne(acc.x) | (bf16rne(acc.y)<<16);
    *(unsigned*)(aggp + (size_t)node*HH + c) = pk;
}

// ---------------- dual-branch node GEMM via MFMA bf16: ct-outer, minimal live accs ----------------
__global__ __launch_bounds__(256) void k_gemm2m(
        const unsigned short* __restrict__ A1, const unsigned short* __restrict__ A2,
        const unsigned short* __restrict__ Bp0, const unsigned short* __restrict__ Bp1,
        const float* __restrict__ b1, const float* __restrict__ b2,
        const float* __restrict__ g1, const float* __restrict__ g2,
        const float* __restrict__ e1, const float* __restrict__ e2,
        float* __restrict__ C, unsigned short* __restrict__ Cb, int n){
    int tx = threadIdx.x;
    int l = tx & 63, wv = tx >> 6;
    int rb = blockIdx.x*LBM + wv*16;
    int mlo = l & 15, khi = l >> 4;
    int arow = rb + mlo;
    bool ok = arow < n;

    // A fragments for both branches, loaded once (8 x short8 = 32 VGPR)
    short8 af0[4], af1[4];
    {
        const short8* ap0 = (const short8*)(A1 + (size_t)arow*HH);
        const short8* ap1 = (const short8*)(A2 + (size_t)arow*HH);
        #pragma unroll
        for (int s=0;s<4;s++){
            af0[s] = ok ? ap0[s*4 + khi] : (short8)0;
            af1[s] = ok ? ap1[s*4 + khi] : (short8)0;
        }
    }
    const short8* bp0 = (const short8*)Bp0;
    const short8* bp1 = (const short8*)Bp1;

    #pragma unroll
    for (int ct=0;ct<8;ct++){
        f32x4 a0 = (f32x4)0.f, a1 = (f32x4)0.f;
        #pragma unroll
        for (int s=0;s<4;s++)
            a0 = __builtin_amdgcn_mfma_f32_16x16x32_bf16(af0[s], bp0[s*512 + ct*64 + l], a0, 0, 0, 0);
        #pragma unroll
        for (int s=0;s<4;s++)
            a1 = __builtin_amdgcn_mfma_f32_16x16x32_bf16(af1[s], bp1[s*512 + ct*64 + l], a1, 0, 0, 0);

        int ncol = ct*16 + mlo;
        float bi1 = b1[ncol], ga1 = g1[ncol], bt1 = e1[ncol];
        float bi2 = b2[ncol], ga2 = g2[ncol], bt2 = e2[ncol];
        #pragma unroll
        for (int r=0;r<4;r++){
            int grow = rb + khi*4 + r;
            if (grow < n){
                float xv = a0[r] + bi1;
                xv = (xv>=0.f)? xv : 0.01f*xv;
                float yv = a1[r] + bi2;
                yv = (yv>=0.f)? yv : 0.01f*yv;
                float o = (ga1*xv + ga2*yv)*BN_INV + bt1 + bt2;
                if (C) C[(size_t)grow*HH + ncol] = o;
                Cb[(size_t)grow*HH + ncol] = (unsigned short)bf16rne(o);
            }
        }
    }
}

// ---------------- fused pool + FC x3 + head ----------------
static __device__ __forceinline__ int lower_bound_i(const int* __restrict__ a, int n, int key){
    int lo=0, hi=n;
    while (lo<hi){ int m=(lo+hi)>>1; if (a[m]<key) lo=m+1; else hi=m; }
    return lo;
}
__global__ void k_poolfc(const float* __restrict__ h,
                     const int* __restrict__ batch,
                     const float* __restrict__ fcW, const float* __restrict__ fcB,
                     const float* __restrict__ fbg, const float* __restrict__ fbb,
                     const float* __restrict__ outW, const float* __restrict__ outB,
                     float* __restrict__ out, int n){
    __shared__ float row[HH];
    __shared__ float red[2];
    int g = blockIdx.x, c = threadIdx.x;
    int lo = lower_bound_i(batch, n, g);
    int hi = lower_bound_i(batch, n, g+1);
    float v = 0.f;
    for (int r=lo; r<hi; r++) v += h[(size_t)r*HH + c];
    for (int l=0;l<3;l++){
        row[c] = v; __syncthreads();
        float acc = fcB[l*HH + c];
        const float* W = fcW + (size_t)l*HH*HH;
        #pragma unroll 8
        for (int k=0;k<HH;k++) acc += row[k]*W[k*HH + c];
        acc = (acc>=0.f)? acc : 0.01f*acc;
        v = fbg[l*HH+c]*acc*BN_INV + fbb[l*HH+c];
        __syncthreads();
    }
    float t = v * outW[c];
    #pragma unroll
    for (int o=32;o>0;o>>=1) t += __shfl_down(t, o, 64);
    if ((c&63)==0) red[c>>6] = t;
    __syncthreads();
    if (c==0) out[g] = red[0] + red[1] + outB[0];
}

extern "C" void kernel_launch(void* const* d_in, const int* in_sizes, int n_in,
                              void* d_out, int out_size, void* d_ws, size_t ws_size,
                              hipStream_t stream){
    const float* x      = (const float*)d_in[0];
    const float* pos    = (const float*)d_in[1];
    const float* W_in   = (const float*)d_in[2];
    const float* b_in   = (const float*)d_in[3];
    const float* coordW = (const float*)d_in[4];
    const float* coordB = (const float*)d_in[5];
    const float* nodeW  = (const float*)d_in[6];
    const float* nodeB  = (const float*)d_in[7];
    const float* bnG    = (const float*)d_in[8];
    const float* bnB    = (const float*)d_in[9];
    const float* fcW    = (const float*)d_in[10];
    const float* fcB    = (const float*)d_in[11];
    const float* fcBnG  = (const float*)d_in[12];
    const float* fcBnB  = (const float*)d_in[13];
    const float* outW   = (const float*)d_in[14];
    const float* outB   = (const float*)d_in[15];
    const int* ei1      = (const int*)d_in[16];
    const int* ei2      = (const int*)d_in[17];
    const int* batch    = (const int*)d_in[18];
    const int E1 = in_sizes[16]/2, E2 = in_sizes[17]/2;
    const int n = NN;
    const int n2 = 2*n;
    const int ET = E1 + E2;

    char* w = (char*)d_ws;
    size_t o = 0;
    auto alloc = [&](size_t bytes)->void*{
        void* r = w + o;
        o += (bytes + 255) & ~(size_t)255;
        return r;
    };
    unsigned short* hb    = (unsigned short*)alloc((size_t)n*HH*2);
    unsigned short* hb2   = (unsigned short*)alloc((size_t)n*HH*2);
    unsigned short* aggb1 = (unsigned short*)alloc((size_t)n*HH*2);
    unsigned short* aggb2 = (unsigned short*)alloc((size_t)n*HH*2);
    unsigned short* Bpk   = (unsigned short*)alloc((size_t)6*16384*2);
    unsigned short* tabs  = (unsigned short*)alloc((size_t)6*NBINS*HH*4);  // fp16 (v,slope)
    float*  Wtg  = (float*)alloc((size_t)128*36*4);
    int*    off  = (int*)alloc((size_t)(n2+1)*4);
    int*    cnt  = (int*)alloc((size_t)n2*4);     // cnt, cur, flags contiguous -> one memset
    int*    cur  = (int*)alloc((size_t)n2*4);
    unsigned* flags = (unsigned*)alloc(1024*4);
    int*    aggl = (int*)alloc(1024*4);
    int*    incl = (int*)alloc(1024*4);
    float2* rec  = (float2*)alloc((size_t)ET*8);
    float*  hfin = (float*)alloc((size_t)n*HH*4);
    (void)n_in; (void)out_size; (void)ws_size;

    int nb2 = (n2+255)/256;   // 782 scan blocks

    hipMemsetAsync(cnt, 0, (size_t)(2*n2 + 1024)*4, stream);
    k_count<<<(ET+255)/256,256,0,stream>>>(ei1, ei2, E1, E2, n, cnt);
    k_scan_lb<<<nb2,256,0,stream>>>(cnt, n2, off, aggl, incl, flags, ET);
    k_build<<<66+6144+(ET+255)/256,256,0,stream>>>(nodeW, coordW, coordB, W_in,
        ei1, ei2, E1, E2, n, pos, off, cur, Bpk, tabs, Wtg, rec);

    k_input<<<2048,256,0,stream>>>(x, Wtg, b_in, hb);

    int nb4 = (n+3)/4;
    unsigned short* hbcur = hb;
    unsigned short* hboth = hb2;
    for (int l=0; l<3; l++){
        int li0 = l*2, li1 = l*2+1;
        float* Cout = (l==2) ? hfin : nullptr;       // fp32 out only on final layer (poolfc)
        k_gather<<<2*nb4,256,0,stream>>>(hbcur, off, rec,
            tabs + (size_t)li0*NBINS*HH*2, tabs + (size_t)li1*NBINS*HH*2,
            aggb1, aggb2, n, nb4);
        k_gemm2m<<<(n+LBM-1)/LBM,256,0,stream>>>(aggb1, aggb2,
            Bpk + (size_t)li0*16384, Bpk + (size_t)li1*16384,
            nodeB + (size_t)li0*HH,  nodeB + (size_t)li1*HH,
            bnG   + (size_t)li0*HH,  bnG   + (size_t)li1*HH,
            bnB   + (size_t)li0*HH,  bnB   + (size_t)li1*HH,
            Cout, hboth, n);
        unsigned short* tb = hbcur; hbcur = hboth; hboth = tb;
    }

    k_poolfc<<<GG,128,0,stream>>>(hfin, batch, fcW, fcB, fcBnG, fcBnB, outW, outB, (float*)d_out, n);
}

// Round 17
// 505.754 us; speedup vs baseline: 1.2267x; 1.0011x over previous
//
#include <hip/hip_runtime.h>
#include <hip/hip_fp16.h>
#include <math.h>

#define NN   100000
#define HH   128
#define INF_ 35
#define GG   1000
#define LBM  64
#define NBINS 2048
#define DSCALE 128.0f      /* NBINS / 16.0 */
#define DINV   0.0078125f  /* 16.0 / NBINS */
#define DCLAMP 15.992f     /* ensures bin <= 2046 */

typedef __attribute__((ext_vector_type(8))) short short8;
typedef __attribute__((ext_vector_type(4))) float f32x4;

static __device__ __forceinline__ float silu_f(float x){ return x / (1.f + __expf(-x)); }
static __device__ __forceinline__ unsigned bf16rne(float x){
    unsigned u = __float_as_uint(x);
    return (u + 0x7FFFu + ((u>>16)&1u)) >> 16;
}
#define BN_INV 0.9999950000374997f  /* 1/sqrt(1+1e-5) */

// ---------------- stacked CSR: count ----------------
__global__ void k_count(const int* __restrict__ ei1, const int* __restrict__ ei2,
                        int E1, int E2, int n, int* __restrict__ deg){
    int e = blockIdx.x*256 + threadIdx.x;
    int ET = E1 + E2;
    if (e >= ET) return;
    int c;
    if (e < E1) c = ei1[E1 + e];
    else        c = n + ei2[E2 + (e - E1)];
    atomicAdd(&deg[c], 1);
}

// ---------------- single-kernel decoupled-lookback exclusive scan ----------------
__global__ void k_scan_lb(const int* __restrict__ deg, int n2, int* __restrict__ off,
                          int* __restrict__ agg, int* __restrict__ incl,
                          unsigned* __restrict__ flags, int ET){
    __shared__ int s[256];
    __shared__ int exc_sh;
    int blk = blockIdx.x, tid = threadIdx.x;
    int i = blk*256 + tid;
    int v = (i<n2)? deg[i] : 0;
    s[tid] = v; __syncthreads();
    for (int ofs=1; ofs<256; ofs<<=1){
        int t = (tid>=ofs)? s[tid-ofs] : 0;
        __syncthreads(); s[tid] += t; __syncthreads();
    }
    if (tid == 0){
        int total = s[255];
        atomicExch(&agg[blk], total);
        __threadfence();
        atomicExch(&flags[blk], 1u);
        int exc = 0;
        int pb = blk - 1;
        while (pb >= 0){
            unsigned f;
            do { f = atomicAdd(&flags[pb], 0u); } while (f == 0u);
            if (f == 2u){ exc += atomicAdd(&incl[pb], 0); break; }
            exc += atomicAdd(&agg[pb], 0);
            pb--;
        }
        atomicExch(&incl[blk], exc + total);
        __threadfence();
        atomicExch(&flags[blk], 2u);
        exc_sh = exc;
    }
    __syncthreads();
    if (i < n2) off[i] = exc_sh + s[tid] - v;
    if (i == 0) off[n2] = ET;
}

// ---------------- fused build: nodeW pack + Wtg + fp16 (v,slope) tables + CSR fill ----------------
// blocks [0,48): pack ; [48,66): Wtg ; [66,6210): table ; [6210,..): fill
__global__ void k_build(const float* __restrict__ nodeW,
                        const float* __restrict__ coordW, const float* __restrict__ coordB,
                        const float* __restrict__ W_in,
                        const int* __restrict__ ei1, const int* __restrict__ ei2,
                        int E1, int E2, int n, const float* __restrict__ pos,
                        const int* __restrict__ off, int* __restrict__ cur,
                        unsigned short* __restrict__ Bpk, unsigned short* __restrict__ tabs,
                        float* __restrict__ Wtg, float2* __restrict__ rec){
    int blk = blockIdx.x, tx = threadIdx.x;
    if (blk < 48){
        int idx = blk*256 + tx;
        if (idx >= 6*2048) return;
        int li = idx >> 11;
        int r  = idx & 2047;
        int s  = r >> 9;
        int r2 = r & 511;
        int ct = r2 >> 6;
        int l  = r2 & 63;
        const float* src = nodeW + (size_t)li*16384 + (size_t)(s*32 + (l>>4)*8)*HH + ct*16 + (l&15);
        unsigned short o[8];
        #pragma unroll
        for (int j=0;j<8;j++) o[j] = (unsigned short)bf16rne(src[(size_t)j*HH]);
        uint4 v;
        v.x = o[0] | ((unsigned)o[1]<<16);
        v.y = o[2] | ((unsigned)o[3]<<16);
        v.z = o[4] | ((unsigned)o[5]<<16);
        v.w = o[6] | ((unsigned)o[7]<<16);
        *(uint4*)(Bpk + (size_t)idx*8) = v;
    } else if (blk < 66){
        int i = (blk-48)*256 + tx;
        if (i >= 128*36) return;
        int c = i/36, k = i - c*36;
        Wtg[i] = (k < INF_) ? W_in[k*HH + c] : 0.f;
    } else if (blk < 66+6144){
        int idx = (blk-66)*256 + tx;
        if (idx >= 6*NBINS*HH) return;
        int li  = idx / (NBINS*HH);
        int rem = idx - li*(NBINS*HH);
        int bin = rem >> 7;
        int col = rem & 127;
        float d0 = (float)bin * DINV;
        float d1 = d0 + DINV;
        const float* cW = coordW + (size_t)li*9*HH;
        float cb = coordB[li*HH + col];
        float q0 = cb, q1 = cb;
        #pragma unroll
        for (int k=0;k<9;k++){
            float wk = cW[k*HH + col];
            float t0 = 1.5f*d0 - 1.125f*(float)k;
            float t1 = 1.5f*d1 - 1.125f*(float)k;
            q0 += __expf(-t0*t0) * wk;
            q1 += __expf(-t1*t1) * wk;
        }
        float v = silu_f(q0);
        float s = silu_f(q1) - v;
        tabs[(size_t)idx*2+0] = __half_as_ushort(__float2half_rn(v));
        tabs[(size_t)idx*2+1] = __half_as_ushort(__float2half_rn(s));
    } else {
        int e = (blk - (66+6144))*256 + tx;
        int ET = E1 + E2;
        if (e >= ET) return;
        int r, creal, cslot;
        if (e < E1){ r = ei1[e];        creal = ei1[E1 + e];        cslot = creal; }
        else       { int ee = e - E1; r = ei2[ee]; creal = ei2[E2 + ee]; cslot = n + creal; }
        int slot = atomicAdd(&cur[cslot], 1);
        int p = off[cslot] + slot;
        float dx = pos[r*3+0]-pos[creal*3+0];
        float dy = pos[r*3+1]-pos[creal*3+1];
        float dz = pos[r*3+2]-pos[creal*3+2];
        float d  = sqrtf(dx*dx + dy*dy + dz*dz);
        rec[p] = make_float2(__int_as_float(r), d);
    }
}

// ---------------- input: hb = bf16(silu(x @ W_in + b)); W streamed from L2 ----------------
#define NT_IN (NN/16)
__global__ __launch_bounds__(256) void k_input(const float* __restrict__ x,
        const float* __restrict__ Wtg, const float* __restrict__ b,
        unsigned short* __restrict__ hb){
    __shared__ __align__(16) float xs[16][36];
    int tx = threadIdx.x;
    int c = tx & 127, g = tx >> 7;
    float bc = b[c];
    const float4* wp = (const float4*)(Wtg + c*36);
    for (int tile = blockIdx.x; tile < NT_IN; tile += gridDim.x){
        int r0 = tile*16;
        for (int i = tx; i < 16*INF_; i += 256){
            int rr = i/INF_, kk = i - rr*INF_;
            xs[rr][kk] = x[(size_t)(r0+rr)*INF_ + kk];
        }
        if (tx < 16) xs[tx][35] = 0.f;
        __syncthreads();
        float acc[8];
        #pragma unroll
        for (int j=0;j<8;j++) acc[j] = bc;
        #pragma unroll
        for (int kk=0;kk<9;kk++){
            float4 w4 = wp[kk];
            #pragma unroll
            for (int j=0;j<8;j++){
                float4 xv = *(const float4*)(&xs[g*8+j][kk*4]);
                acc[j] += xv.x*w4.x + xv.y*w4.y + xv.z*w4.z + xv.w*w4.w;
            }
        }
        #pragma unroll
        for (int j=0;j<8;j++){
            int gr = r0 + g*8 + j;
            hb[(size_t)gr*HH + c] = (unsigned short)bf16rne(silu_f(acc[j]));
        }
        __syncthreads();
    }
}

// ---------------- merged dual-branch gather: fp16 (v,slope) table, bf16 h, 4-edge unroll ----------------
#define GEDGE(RP, S_, B_, F_)                                        \
    int S_ = __float_as_int((RP).x);                                 \
    float db_##S_ = fminf((RP).y, DCLAMP)*DSCALE;                    \
    int B_ = (int)db_##S_; float F_ = db_##S_ - (float)B_;

#define GACC(U_, T_, F_)                                             \
    {                                                                \
        float2 p0 = __half22float2(*(const __half2*)&(T_).x);        \
        float2 p1 = __half22float2(*(const __half2*)&(T_).y);        \
        acc.x += __uint_as_float((U_)<<16)           * (p0.x + p0.y*(F_)); \
        acc.y += __uint_as_float((U_) & 0xFFFF0000u) * (p1.x + p1.y*(F_)); \
    }

__global__ __launch_bounds__(256) void k_gather(
        const unsigned short* __restrict__ hb,
        const int* __restrict__ off, const float2* __restrict__ rec,
        const unsigned short* __restrict__ tab0, const unsigned short* __restrict__ tab1,
        unsigned short* __restrict__ aggb1, unsigned short* __restrict__ aggb2,
        int n, int nblk1){
    int b = blockIdx.x;
    int br = (b >= nblk1) ? 1 : 0;
    int node = (br ? b - nblk1 : b)*4 + (threadIdx.x>>6);
    if (node >= n) return;
    int c = (threadIdx.x & 63)*2;
    const unsigned short* tab = br ? tab1 : tab0;
    unsigned short* aggp = br ? aggb2 : aggb1;

    float2 acc;
    {
        unsigned u = *(const unsigned*)(hb + (size_t)node*HH + c);
        acc.x = __uint_as_float(u<<16); acc.y = __uint_as_float(u & 0xFFFF0000u);
    }

    int slot = node + br*n;
    int lo = off[slot], hi = off[slot+1];
    lo = __builtin_amdgcn_readfirstlane(lo);
    hi = __builtin_amdgcn_readfirstlane(hi);

    int p = lo;
    for (; p+4<=hi; p+=4){
        float2 r0 = rec[p], r1 = rec[p+1], r2 = rec[p+2], r3 = rec[p+3];
        GEDGE(r0, s0, b0, f0)
        GEDGE(r1, s1, b1, f1)
        GEDGE(r2, s2, b2, f2)
        GEDGE(r3, s3, b3, f3)
        unsigned u0 = *(const unsigned*)(hb + (size_t)s0*HH + c);
        unsigned u1 = *(const unsigned*)(hb + (size_t)s1*HH + c);
        unsigned u2 = *(const unsigned*)(hb + (size_t)s2*HH + c);
        unsigned u3 = *(const unsigned*)(hb + (size_t)s3*HH + c);
        uint2 t0 = *(const uint2*)(tab + ((size_t)b0*HH + c)*2);
        uint2 t1 = *(const uint2*)(tab + ((size_t)b1*HH + c)*2);
        uint2 t2 = *(const uint2*)(tab + ((size_t)b2*HH + c)*2);
        uint2 t3 = *(const uint2*)(tab + ((size_t)b3*HH + c)*2);
        GACC(u0, t0, f0)
        GACC(u1, t1, f1)
        GACC(u2, t2, f2)
        GACC(u3, t3, f3)
    }
    for (; p+2<=hi; p+=2){
        float2 r0 = rec[p], r1 = rec[p+1];
        GEDGE(r0, s0, b0, f0)
        GEDGE(r1, s1, b1, f1)
        unsigned u0 = *(const unsigned*)(hb + (size_t)s0*HH + c);
        unsigned u1 = *(const unsigned*)(hb + (size_t)s1*HH + c);
        uint2 t0 = *(const uint2*)(tab + ((size_t)b0*HH + c)*2);
        uint2 t1 = *(const uint2*)(tab + ((size_t)b1*HH + c)*2);
        GACC(u0, t0, f0)
        GACC(u1, t1, f1)
    }
    if (p < hi){
        float2 r0 = rec[p];
        GEDGE(r0, s0, b0, f0)
        unsigned u0 = *(const unsigned*)(hb + (size_t)s0*HH + c);
        uint2 t0 = *(const uint2*)(tab + ((size_t)b0*HH + c)*2);
        GACC(u0, t0, f0)
    }
    unsigned pk = bf16rne(acc.x) | (bf16rne(acc.y)<<16);
    *(unsigned*)(aggp + (size_t)node*HH + c) = pk;
}

// ---------------- dual-branch node GEMM via MFMA bf16: ct-pair, bf16-only output ----------------
__global__ __launch_bounds__(256) void k_gemm2m(
        const unsigned short* __restrict__ A1, const unsigned short* __restrict__ A2,
        const unsigned short* __restrict__ Bp0, const unsigned short* __restrict__ Bp1,
        const float* __restrict__ b1, const float* __restrict__ b2,
        const float* __restrict__ g1, const float* __restrict__ g2,
        const float* __restrict__ e1, const float* __restrict__ e2,
        unsigned short* __restrict__ Cb, int n){
    int tx = threadIdx.x;
    int l = tx & 63, wv = tx >> 6;
    int rb = blockIdx.x*LBM + wv*16;
    int mlo = l & 15, khi = l >> 4;
    int arow = rb + mlo;
    bool ok = arow < n;

    short8 af0[4], af1[4];
    {
        const short8* ap0 = (const short8*)(A1 + (size_t)arow*HH);
        const short8* ap1 = (const short8*)(A2 + (size_t)arow*HH);
        #pragma unroll
        for (int s=0;s<4;s++){
            af0[s] = ok ? ap0[s*4 + khi] : (short8)0;
            af1[s] = ok ? ap1[s*4 + khi] : (short8)0;
        }
    }
    const short8* bp0 = (const short8*)Bp0;
    const short8* bp1 = (const short8*)Bp1;

    #pragma unroll
    for (int ct=0;ct<8;ct+=2){
        f32x4 aA0 = (f32x4)0.f, aA1 = (f32x4)0.f;   // branch0, cols ct / ct+1
        f32x4 aB0 = (f32x4)0.f, aB1 = (f32x4)0.f;   // branch1
        #pragma unroll
        for (int s=0;s<4;s++){
            short8 bf0 = bp0[s*512 + ct*64 + l];
            short8 bf1 = bp0[s*512 + (ct+1)*64 + l];
            aA0 = __builtin_amdgcn_mfma_f32_16x16x32_bf16(af0[s], bf0, aA0, 0, 0, 0);
            aA1 = __builtin_amdgcn_mfma_f32_16x16x32_bf16(af0[s], bf1, aA1, 0, 0, 0);
        }
        #pragma unroll
        for (int s=0;s<4;s++){
            short8 bf0 = bp1[s*512 + ct*64 + l];
            short8 bf1 = bp1[s*512 + (ct+1)*64 + l];
            aB0 = __builtin_amdgcn_mfma_f32_16x16x32_bf16(af1[s], bf0, aB0, 0, 0, 0);
            aB1 = __builtin_amdgcn_mfma_f32_16x16x32_bf16(af1[s], bf1, aB1, 0, 0, 0);
        }
        #pragma unroll
        for (int half=0;half<2;half++){
            int ncol = (ct+half)*16 + mlo;
            f32x4 aA = half ? aA1 : aA0;
            f32x4 aB = half ? aB1 : aB0;
            float bi1 = b1[ncol], ga1 = g1[ncol], bt1 = e1[ncol];
            float bi2 = b2[ncol], ga2 = g2[ncol], bt2 = e2[ncol];
            #pragma unroll
            for (int r=0;r<4;r++){
                int grow = rb + khi*4 + r;
                if (grow < n){
                    float xv = aA[r] + bi1;
                    xv = (xv>=0.f)? xv : 0.01f*xv;
                    float yv = aB[r] + bi2;
                    yv = (yv>=0.f)? yv : 0.01f*yv;
                    float o = (ga1*xv + ga2*yv)*BN_INV + bt1 + bt2;
                    Cb[(size_t)grow*HH + ncol] = (unsigned short)bf16rne(o);
                }
            }
        }
    }
}

// ---------------- fused pool + FC x3 + head (bf16 h input) ----------------
static __device__ __forceinline__ int lower_bound_i(const int* __restrict__ a, int n, int key){
    int lo=0, hi=n;
    while (lo<hi){ int m=(lo+hi)>>1; if (a[m]<key) lo=m+1; else hi=m; }
    return lo;
}
__global__ void k_poolfc(const unsigned short* __restrict__ hb,
                     const int* __restrict__ batch,
                     const float* __restrict__ fcW, const float* __restrict__ fcB,
                     const float* __restrict__ fbg, const float* __restrict__ fbb,
                     const float* __restrict__ outW, const float* __restrict__ outB,
                     float* __restrict__ out, int n){
    __shared__ float row[HH];
    __shared__ float red[2];
    int g = blockIdx.x, c = threadIdx.x;
    int lo = lower_bound_i(batch, n, g);
    int hi = lower_bound_i(batch, n, g+1);
    float v = 0.f;
    for (int r=lo; r<hi; r++)
        v += __uint_as_float(((unsigned)hb[(size_t)r*HH + c])<<16);
    for (int l=0;l<3;l++){
        row[c] = v; __syncthreads();
        float acc = fcB[l*HH + c];
        const float* W = fcW + (size_t)l*HH*HH;
        #pragma unroll 8
        for (int k=0;k<HH;k++) acc += row[k]*W[k*HH + c];
        acc = (acc>=0.f)? acc : 0.01f*acc;
        v = fbg[l*HH+c]*acc*BN_INV + fbb[l*HH+c];
        __syncthreads();
    }
    float t = v * outW[c];
    #pragma unroll
    for (int o=32;o>0;o>>=1) t += __shfl_down(t, o, 64);
    if ((c&63)==0) red[c>>6] = t;
    __syncthreads();
    if (c==0) out[g] = red[0] + red[1] + outB[0];
}

extern "C" void kernel_launch(void* const* d_in, const int* in_sizes, int n_in,
                              void* d_out, int out_size, void* d_ws, size_t ws_size,
                              hipStream_t stream){
    const float* x      = (const float*)d_in[0];
    const float* pos    = (const float*)d_in[1];
    const float* W_in   = (const float*)d_in[2];
    const float* b_in   = (const float*)d_in[3];
    const float* coordW = (const float*)d_in[4];
    const float* coordB = (const float*)d_in[5];
    const float* nodeW  = (const float*)d_in[6];
    const float* nodeB  = (const float*)d_in[7];
    const float* bnG    = (const float*)d_in[8];
    const float* bnB    = (const float*)d_in[9];
    const float* fcW    = (const float*)d_in[10];
    const float* fcB    = (const float*)d_in[11];
    const float* fcBnG  = (const float*)d_in[12];
    const float* fcBnB  = (const float*)d_in[13];
    const float* outW   = (const float*)d_in[14];
    const float* outB   = (const float*)d_in[15];
    const int* ei1      = (const int*)d_in[16];
    const int* ei2      = (const int*)d_in[17];
    const int* batch    = (const int*)d_in[18];
    const int E1 = in_sizes[16]/2, E2 = in_sizes[17]/2;
    const int n = NN;
    const int n2 = 2*n;
    const int ET = E1 + E2;

    char* w = (char*)d_ws;
    size_t o = 0;
    auto alloc = [&](size_t bytes)->void*{
        void* r = w + o;
        o += (bytes + 255) & ~(size_t)255;
        return r;
    };
    unsigned short* hb    = (unsigned short*)alloc((size_t)n*HH*2);
    unsigned short* hb2   = (unsigned short*)alloc((size_t)n*HH*2);
    unsigned short* aggb1 = (unsigned short*)alloc((size_t)n*HH*2);
    unsigned short* aggb2 = (unsigned short*)alloc((size_t)n*HH*2);
    unsigned short* Bpk   = (unsigned short*)alloc((size_t)6*16384*2);
    unsigned short* tabs  = (unsigned short*)alloc((size_t)6*NBINS*HH*4);  // fp16 (v,slope)
    float*  Wtg  = (float*)alloc((size_t)128*36*4);
    int*    off  = (int*)alloc((size_t)(n2+1)*4);
    int*    cnt  = (int*)alloc((size_t)n2*4);     // cnt, cur, flags contiguous -> one memset
    int*    cur  = (int*)alloc((size_t)n2*4);
    unsigned* flags = (unsigned*)alloc(1024*4);
    int*    aggl = (int*)alloc(1024*4);
    int*    incl = (int*)alloc(1024*4);
    float2* rec  = (float2*)alloc((size_t)ET*8);
    (void)n_in; (void)out_size; (void)ws_size;

    int nb2 = (n2+255)/256;   // 782 scan blocks

    hipMemsetAsync(cnt, 0, (size_t)(2*n2 + 1024)*4, stream);
    k_count<<<(ET+255)/256,256,0,stream>>>(ei1, ei2, E1, E2, n, cnt);
    k_scan_lb<<<nb2,256,0,stream>>>(cnt, n2, off, aggl, incl, flags, ET);
    k_build<<<66+6144+(ET+255)/256,256,0,stream>>>(nodeW, coordW, coordB, W_in,
        ei1, ei2, E1, E2, n, pos, off, cur, Bpk, tabs, Wtg, rec);

    k_input<<<2048,256,0,stream>>>(x, Wtg, b_in, hb);

    int nb4 = (n+3)/4;
    unsigned short* hbcur = hb;
    unsigned short* hboth = hb2;
    for (int l=0; l<3; l++){
        int li0 = l*2, li1 = l*2+1;
        k_gather<<<2*nb4,256,0,stream>>>(hbcur, off, rec,
            tabs + (size_t)li0*NBINS*HH*2, tabs + (size_t)li1*NBINS*HH*2,
            aggb1, aggb2, n, nb4);
        k_gemm2m<<<(n+LBM-1)/LBM,256,0,stream>>>(aggb1, aggb2,
            Bpk + (size_t)li0*16384, Bpk + (size_t)li1*16384,
            nodeB + (size_t)li0*HH,  nodeB + (size_t)li1*HH,
            bnG   + (size_t)li0*HH,  bnG   + (size_t)li1*HH,
            bnB   + (size_t)li0*HH,  bnB   + (size_t)li1*HH,
            hboth, n);
        unsigned short* tb = hbcur; hbcur = hboth; hboth = tb;
    }

    k_poolfc<<<GG,128,0,stream>>>(hbcur, batch, fcW, fcB, fcBnG, fcBnB, outW, outB, (float*)d_out, n);
}